// Round 5
// baseline (327.736 us; speedup 1.0000x reference)
//
#include <hip/hip_runtime.h>

#define BATCH 8
#define CCH 8
#define HW 262144       // 512*512
#define SEGS 16         // segments 1..16 (segment 0 provably ignored by the reference)
#define BX 64           // blocks per batch slice

// Native fp32 global atomic add (fire-and-forget, no CAS loop).
__device__ __forceinline__ void fadd(float* p, float v) { unsafeAtomicAdd(p, v); }

// ws float layout:
//   [0, 128)      counts[b][s]
//   [128, 1152)   sums[b][s][c]
//   [1152, 1280)  pen_sum[b][s]

// Pure-VALU accumulation: no per-pixel LDS ops at all. Each wave handles 2
// channels over the block's 1024-quad strip; acc/cnt live in registers,
// selected via cmp+cndmask, reduced by shfl_xor butterfly (uniform swizzle
// pattern = fast DS path), flushed by lane 0 via native global atomics.
__global__ __launch_bounds__(256, 4) void accum_kernel(
    const float* __restrict__ emb, const int* __restrict__ lab,
    const int* __restrict__ msk, float* __restrict__ ws)
{
    const int b = blockIdx.y;
    const int w = threadIdx.x >> 6;          // wave 0..3 -> channels 2w, 2w+1
    const int lane = threadIdx.x & 63;
    const int c0 = 2 * w;

    const float4* e0p = (const float4*)(emb + ((size_t)b * CCH + c0) * HW);
    const float4* e1p = (const float4*)(emb + ((size_t)b * CCH + c0 + 1) * HW);
    const int4* lb = (const int4*)(lab + (size_t)b * HW);
    const int4* mb = (const int4*)(msk + (size_t)b * HW);

    float acc0[SEGS], acc1[SEGS];
    float cnt[4];                            // wave w owns counts for segs 4w..4w+3
#pragma unroll
    for (int s = 0; s < SEGS; ++s) { acc0[s] = 0.f; acc1[s] = 0.f; }
    cnt[0] = cnt[1] = cnt[2] = cnt[3] = 0.f;
    const int csbase = 4 * w + 1;            // id value for cnt[0]

    const int qbase = blockIdx.x * 1024;     // 1024 quads per block strip
#pragma unroll 2
    for (int it = 0; it < 16; ++it) {
        const int q = qbase + it * 64 + lane;
        int4 l4 = lb[q];
        int4 m4 = mb[q];
        float4 e04 = e0p[q];
        float4 e14 = e1p[q];
        int id[4] = { m4.x ? l4.x : 0, m4.y ? l4.y : 0, m4.z ? l4.z : 0, m4.w ? l4.w : 0 };
        float ev0[4] = {e04.x, e04.y, e04.z, e04.w};
        float ev1[4] = {e14.x, e14.y, e14.z, e14.w};
#pragma unroll
        for (int j = 0; j < 4; ++j) {
            const int idj = id[j];
            const float a = ev0[j], bb = ev1[j];
#pragma unroll
            for (int s = 0; s < SEGS; ++s) {
                float m = (idj == s + 1) ? 1.f : 0.f;   // cmp + cndmask
                acc0[s] += m * a;                        // fmac
                acc1[s] += m * bb;                       // fmac
            }
#pragma unroll
            for (int k = 0; k < 4; ++k)
                cnt[k] += (idj == csbase + k) ? 1.f : 0.f;
        }
    }

    // butterfly reduce 36 values across the 64-lane wave (uniform swizzles)
#pragma unroll
    for (int m = 1; m < 64; m <<= 1) {
#pragma unroll
        for (int s = 0; s < SEGS; ++s) {
            acc0[s] += __shfl_xor(acc0[s], m);
            acc1[s] += __shfl_xor(acc1[s], m);
        }
#pragma unroll
        for (int k = 0; k < 4; ++k) cnt[k] += __shfl_xor(cnt[k], m);
    }

    if (lane == 0) {
        float* sums = ws + 128 + (size_t)b * SEGS * CCH;
#pragma unroll
        for (int s = 0; s < SEGS; ++s) {
            if (acc0[s] != 0.f) fadd(&sums[s * CCH + c0], acc0[s]);
            if (acc1[s] != 0.f) fadd(&sums[s * CCH + c0 + 1], acc1[s]);
        }
#pragma unroll
        for (int k = 0; k < 4; ++k)
            if (cnt[k] != 0.f) fadd(&ws[b * SEGS + 4 * w + k], cnt[k]);
    }
}

// Pure-VALU pull: means live in 128 registers; per-pixel mean selected via
// 4-level cndmask binary tree on the bits of (id-1); pen scatter into 16
// registers via cndmask; butterfly + lane-0 global-atomic flush.
__global__ __launch_bounds__(256, 2) void pull_kernel(
    const float* __restrict__ emb, const int* __restrict__ lab,
    const int* __restrict__ msk, float* __restrict__ ws)
{
    const int b = blockIdx.y;
    const int lane = threadIdx.x & 63;

    // load means (uniform across block -> L1 broadcast), keep in registers
    float mu[SEGS][CCH];
#pragma unroll
    for (int s = 0; s < SEGS; ++s) {
        float cv = ws[b * SEGS + s];
        float inv = 1.0f / fmaxf(cv, 1.0f);
#pragma unroll
        for (int c = 0; c < CCH; ++c)
            mu[s][c] = ws[128 + (b * SEGS + s) * CCH + c] * inv;
    }

    float pen[SEGS];
#pragma unroll
    for (int s = 0; s < SEGS; ++s) pen[s] = 0.f;

    const float* ebase = emb + (size_t)b * CCH * HW;
    const int4* lb = (const int4*)(lab + (size_t)b * HW);
    const int4* mb = (const int4*)(msk + (size_t)b * HW);

#pragma unroll
    for (int k = 0; k < 4; ++k) {            // 4 quads per thread
        const int q = blockIdx.x * 1024 + k * 256 + threadIdx.x;
        int4 l4 = lb[q];
        int4 m4 = mb[q];
        float4 e4[CCH];
#pragma unroll
        for (int c = 0; c < CCH; ++c)
            e4[c] = ((const float4*)(ebase + (size_t)c * HW))[q];
        int id[4] = { m4.x ? l4.x : 0, m4.y ? l4.y : 0, m4.z ? l4.z : 0, m4.w ? l4.w : 0 };
#pragma unroll
        for (int j = 0; j < 4; ++j) {
            const int idj = id[j];
            const int ix = (idj > 0) ? idj - 1 : 0;
            const bool b0 = ix & 1, b1 = ix & 2, b2 = ix & 4, b3 = ix & 8;
            float ss = 0.f;
#pragma unroll
            for (int c = 0; c < CCH; ++c) {
                float s01 = b0 ? mu[1][c]  : mu[0][c];
                float s23 = b0 ? mu[3][c]  : mu[2][c];
                float s45 = b0 ? mu[5][c]  : mu[4][c];
                float s67 = b0 ? mu[7][c]  : mu[6][c];
                float s89 = b0 ? mu[9][c]  : mu[8][c];
                float sab = b0 ? mu[11][c] : mu[10][c];
                float scd = b0 ? mu[13][c] : mu[12][c];
                float sef = b0 ? mu[15][c] : mu[14][c];
                float t0 = b1 ? s23 : s01;
                float t1 = b1 ? s67 : s45;
                float t2 = b1 ? sab : s89;
                float t3 = b1 ? sef : scd;
                float u0 = b2 ? t1 : t0;
                float u1 = b2 ? t3 : t2;
                float mv = b3 ? u1 : u0;
                float d = ((const float*)&e4[c])[j] - mv;
                ss += d * d;
            }
            float d = sqrtf(fmaxf(ss, 1e-12f));
            float h = fmaxf(d - 0.5f, 0.f);
            float h2 = h * h;
#pragma unroll
            for (int s = 0; s < SEGS; ++s)
                pen[s] += (idj == s + 1) ? h2 : 0.f;
        }
    }

#pragma unroll
    for (int m = 1; m < 64; m <<= 1)
#pragma unroll
        for (int s = 0; s < SEGS; ++s)
            pen[s] += __shfl_xor(pen[s], m);

    if (lane == 0) {
#pragma unroll
        for (int s = 0; s < SEGS; ++s)
            if (pen[s] != 0.f) fadd(&ws[1152 + b * SEGS + s], pen[s]);
    }
}

__global__ __launch_bounds__(256) void finalize_kernel(
    const float* __restrict__ ws, float* __restrict__ out)
{
    __shared__ float cnt[BATCH][SEGS];
    __shared__ float mu[BATCH][SEGS][CCH];
    __shared__ float pen[BATCH][SEGS];
    __shared__ float res[BATCH][3];

    for (int i = threadIdx.x; i < BATCH * SEGS; i += 256) {
        (&cnt[0][0])[i] = ws[i];
        (&pen[0][0])[i] = ws[1152 + i];
    }
    for (int i = threadIdx.x; i < BATCH * SEGS * CCH; i += 256) {
        float c = ws[i / CCH];
        (&mu[0][0][0])[i] = ws[128 + i] / fmaxf(c, 1.0f);
    }
    __syncthreads();

    const int b = threadIdx.x >> 5;   // 8 batches x 32-lane groups
    const int l = threadIdx.x & 31;

    float pullv = 0.f, Kf = 0.f;
    if (l < SEGS && cnt[b][l] > 0.f) {
        Kf = 1.f;
        pullv = pen[b][l] / cnt[b][l];
    }
    float hs = 0.f, np = 0.f;
    for (int p = l; p < 256; p += 32) {
        int i = p >> 4, j = p & 15;
        if (i < j && cnt[b][i] > 0.f && cnt[b][j] > 0.f) {
            float ssq = 0.f;
#pragma unroll
            for (int c = 0; c < CCH; ++c) {
                float d = mu[b][i][c] - mu[b][j][c];
                ssq += d * d;
            }
            float dist = sqrtf(fmaxf(ssq, 1e-12f));
            float h = fmaxf(3.0f - dist, 0.f);   // 2*DELTA_D = 3.0
            hs += h * h;
            np += 1.f;
        }
    }
#pragma unroll
    for (int m = 16; m >= 1; m >>= 1) {
        pullv += __shfl_xor(pullv, m);
        Kf    += __shfl_xor(Kf, m);
        hs    += __shfl_xor(hs, m);
        np    += __shfl_xor(np, m);
    }
    if (l == 0) {
        res[b][0] = (Kf > 0.f) ? pullv / Kf : 0.f;
        res[b][1] = (np > 0.f) ? hs / np : 0.f;
        res[b][2] = (Kf > 0.f) ? 1.f : 0.f;
    }
    __syncthreads();
    if (threadIdx.x == 0) {
        float sp = 0.f, sh = 0.f, nv = 0.f;
        for (int bb = 0; bb < BATCH; ++bb) {
            sp += res[bb][0] * res[bb][2];
            sh += res[bb][1] * res[bb][2];
            nv += res[bb][2];
        }
        nv = fmaxf(nv, 1.f);
        out[0] = sp / nv;
        out[1] = sh / nv;
    }
}

extern "C" void kernel_launch(void* const* d_in, const int* in_sizes, int n_in,
                              void* d_out, int out_size, void* d_ws, size_t ws_size,
                              hipStream_t stream)
{
    const float* emb = (const float*)d_in[0];
    const int* lab = (const int*)d_in[1];
    const int* msk = (const int*)d_in[2];
    float* out = (float*)d_out;
    float* ws = (float*)d_ws;

    hipMemsetAsync(d_ws, 0, 1280 * sizeof(float), stream);
    dim3 grid(BX, BATCH);
    accum_kernel<<<grid, 256, 0, stream>>>(emb, lab, msk, ws);
    pull_kernel<<<grid, 256, 0, stream>>>(emb, lab, msk, ws);
    finalize_kernel<<<1, 256, 0, stream>>>(ws, out);
}

// Round 6
// 162.475 us; speedup vs baseline: 2.0172x; 2.0172x over previous
//
#include <hip/hip_runtime.h>

#define BATCH 8
#define CCH 8
#define HW 262144       // 512*512
#define SEGS 16         // segments 1..16 (segment 0 provably ignored by the reference)
#define GX 256          // blocks per batch slice; 256 blocks x 256 thr x 1 quad = HW/4

// Native fp32 atomic add (no CAS loop); works for both global and LDS pointers.
__device__ __forceinline__ void fadd(float* p, float v) { unsafeAtomicAdd(p, v); }

// ws float layout:
//   [0, 128)      counts[b][s]
//   [128, 1152)   sums[b][s][c]
//   [1152, 1280)  pen_sum[b][s]

// Latency-bound fix: 1 quad/thread, all 10 independent 16B loads issued
// back-to-back (label/mask first, then 8 embedding channels), high occupancy
// (grid 2048, VGPR cap 85 via launch_bounds) -> ~200+ loads in flight per CU.
__global__ __launch_bounds__(256, 6) void accum_kernel(
    const float* __restrict__ emb, const int* __restrict__ lab,
    const int* __restrict__ msk, float* __restrict__ ws)
{
    const int b = blockIdx.y;
    const int wave = threadIdx.x >> 6;
    // stride-9: for fixed c, banks (9s+c)%32 are 16 distinct banks over s=0..15
    __shared__ float lsum[4][SEGS][9];
    __shared__ float lcnt[4][SEGS + 1];
    for (int i = threadIdx.x; i < 4 * SEGS * 9; i += 256) (&lsum[0][0][0])[i] = 0.f;
    for (int i = threadIdx.x; i < 4 * (SEGS + 1); i += 256) (&lcnt[0][0])[i] = 0.f;
    __syncthreads();

    const int q = blockIdx.x * 256 + threadIdx.x;
    const float* ebase = emb + (size_t)b * CCH * HW;

    // ---- issue all 10 loads; first consumer only needs the 2 oldest ----
    int4 l4 = ((const int4*)(lab + (size_t)b * HW))[q];
    int4 m4 = ((const int4*)(msk + (size_t)b * HW))[q];
    float4 e[CCH];
#pragma unroll
    for (int c = 0; c < CCH; ++c)
        e[c] = ((const float4*)(ebase + (size_t)c * HW))[q];

    int id[4] = { m4.x ? l4.x : 0, m4.y ? l4.y : 0, m4.z ? l4.z : 0, m4.w ? l4.w : 0 };

    float* ls = &lsum[wave][0][0];
    float* lc = &lcnt[wave][0];
    // count atomics first: they cover the latency of e[0..] still in flight
#pragma unroll
    for (int j = 0; j < 4; ++j)
        if (id[j]) fadd(&lc[id[j] - 1], 1.0f);
#pragma unroll
    for (int c = 0; c < CCH; ++c) {
#pragma unroll
        for (int j = 0; j < 4; ++j)
            if (id[j]) fadd(&ls[(id[j] - 1) * 9 + c], ((const float*)&e[c])[j]);
    }
    __syncthreads();

    if (threadIdx.x < SEGS * CCH) {
        const int s = threadIdx.x >> 3, c = threadIdx.x & 7;
        float v = lsum[0][s][c] + lsum[1][s][c] + lsum[2][s][c] + lsum[3][s][c];
        if (v != 0.f) fadd(&ws[128 + (b * SEGS + s) * CCH + c], v);
    } else if (threadIdx.x < SEGS * CCH + SEGS) {
        const int s = threadIdx.x - SEGS * CCH;
        float v = lcnt[0][s] + lcnt[1][s] + lcnt[2][s] + lcnt[3][s];
        if (v != 0.f) fadd(&ws[b * SEGS + s], v);
    }
}

__global__ __launch_bounds__(256, 6) void pull_kernel(
    const float* __restrict__ emb, const int* __restrict__ lab,
    const int* __restrict__ msk, float* __restrict__ ws)
{
    const int b = blockIdx.y;
    const int wave = threadIdx.x >> 6;
    // mt[c][s]: for fixed c the 16 gather targets live in 16 distinct banks;
    // lanes sharing an address broadcast -> conflict-free divergent gather.
    __shared__ float mt[CCH][SEGS];
    __shared__ float lpen[4][SEGS + 1];
    for (int i = threadIdx.x; i < 4 * (SEGS + 1); i += 256) (&lpen[0][0])[i] = 0.f;
    if (threadIdx.x < SEGS * CCH) {
        const int s = threadIdx.x & 15, c = threadIdx.x >> 4;
        float cnt = ws[b * SEGS + s];
        mt[c][s] = ws[128 + (b * SEGS + s) * CCH + c] / fmaxf(cnt, 1.0f);
    }
    __syncthreads();

    const int q = blockIdx.x * 256 + threadIdx.x;
    const float* ebase = emb + (size_t)b * CCH * HW;

    int4 l4 = ((const int4*)(lab + (size_t)b * HW))[q];
    int4 m4 = ((const int4*)(msk + (size_t)b * HW))[q];
    float4 e[CCH];
#pragma unroll
    for (int c = 0; c < CCH; ++c)
        e[c] = ((const float4*)(ebase + (size_t)c * HW))[q];

    int id[4] = { m4.x ? l4.x : 0, m4.y ? l4.y : 0, m4.z ? l4.z : 0, m4.w ? l4.w : 0 };
    int ix[4];
#pragma unroll
    for (int j = 0; j < 4; ++j) ix[j] = id[j] ? id[j] - 1 : 0;

    float ss[4] = {0.f, 0.f, 0.f, 0.f};
#pragma unroll
    for (int c = 0; c < CCH; ++c) {
#pragma unroll
        for (int j = 0; j < 4; ++j) {
            float d = ((const float*)&e[c])[j] - mt[c][ix[j]];
            ss[j] += d * d;
        }
    }
    float* lp = &lpen[wave][0];
#pragma unroll
    for (int j = 0; j < 4; ++j) {
        if (id[j]) {
            float d = sqrtf(fmaxf(ss[j], 1e-12f));
            float h = fmaxf(d - 0.5f, 0.f);
            fadd(&lp[ix[j]], h * h);
        }
    }
    __syncthreads();
    if (threadIdx.x < SEGS) {
        const int s = threadIdx.x;
        float v = lpen[0][s] + lpen[1][s] + lpen[2][s] + lpen[3][s];
        if (v != 0.f) fadd(&ws[1152 + b * SEGS + s], v);
    }
}

__global__ __launch_bounds__(256) void finalize_kernel(
    const float* __restrict__ ws, float* __restrict__ out)
{
    __shared__ float cnt[BATCH][SEGS];
    __shared__ float mu[BATCH][SEGS][CCH];
    __shared__ float pen[BATCH][SEGS];
    __shared__ float res[BATCH][3];

    for (int i = threadIdx.x; i < BATCH * SEGS; i += 256) {
        (&cnt[0][0])[i] = ws[i];
        (&pen[0][0])[i] = ws[1152 + i];
    }
    for (int i = threadIdx.x; i < BATCH * SEGS * CCH; i += 256) {
        float c = ws[i / CCH];
        (&mu[0][0][0])[i] = ws[128 + i] / fmaxf(c, 1.0f);
    }
    __syncthreads();

    const int b = threadIdx.x >> 5;   // 8 batches x 32-lane groups
    const int l = threadIdx.x & 31;

    float pullv = 0.f, Kf = 0.f;
    if (l < SEGS && cnt[b][l] > 0.f) {
        Kf = 1.f;
        pullv = pen[b][l] / cnt[b][l];
    }
    float hs = 0.f, np = 0.f;
    for (int p = l; p < 256; p += 32) {
        int i = p >> 4, j = p & 15;
        if (i < j && cnt[b][i] > 0.f && cnt[b][j] > 0.f) {
            float ssq = 0.f;
#pragma unroll
            for (int c = 0; c < CCH; ++c) {
                float d = mu[b][i][c] - mu[b][j][c];
                ssq += d * d;
            }
            float dist = sqrtf(fmaxf(ssq, 1e-12f));
            float h = fmaxf(3.0f - dist, 0.f);   // 2*DELTA_D = 3.0
            hs += h * h;
            np += 1.f;
        }
    }
#pragma unroll
    for (int m = 16; m >= 1; m >>= 1) {
        pullv += __shfl_xor(pullv, m);
        Kf    += __shfl_xor(Kf, m);
        hs    += __shfl_xor(hs, m);
        np    += __shfl_xor(np, m);
    }
    if (l == 0) {
        res[b][0] = (Kf > 0.f) ? pullv / Kf : 0.f;
        res[b][1] = (np > 0.f) ? hs / np : 0.f;
        res[b][2] = (Kf > 0.f) ? 1.f : 0.f;
    }
    __syncthreads();
    if (threadIdx.x == 0) {
        float sp = 0.f, sh = 0.f, nv = 0.f;
        for (int bb = 0; bb < BATCH; ++bb) {
            sp += res[bb][0] * res[bb][2];
            sh += res[bb][1] * res[bb][2];
            nv += res[bb][2];
        }
        nv = fmaxf(nv, 1.f);
        out[0] = sp / nv;
        out[1] = sh / nv;
    }
}

extern "C" void kernel_launch(void* const* d_in, const int* in_sizes, int n_in,
                              void* d_out, int out_size, void* d_ws, size_t ws_size,
                              hipStream_t stream)
{
    const float* emb = (const float*)d_in[0];
    const int* lab = (const int*)d_in[1];
    const int* msk = (const int*)d_in[2];
    float* out = (float*)d_out;
    float* ws = (float*)d_ws;

    hipMemsetAsync(d_ws, 0, 1280 * sizeof(float), stream);
    dim3 grid(GX, BATCH);   // 2048 blocks, 1 quad/thread
    accum_kernel<<<grid, 256, 0, stream>>>(emb, lab, msk, ws);
    pull_kernel<<<grid, 256, 0, stream>>>(emb, lab, msk, ws);
    finalize_kernel<<<1, 256, 0, stream>>>(ws, out);
}